// Round 2
// baseline (419.913 us; speedup 1.0000x reference)
//
#include <hip/hip_runtime.h>
#include <hip/hip_bf16.h>

#define ETA_C  0.1f
#define BETA_C 0.05f
#define MU_C   0.05f
#define MINI_C 1e-6f

// ---------- DPP wave-64 sum (used once per wave at the end, not per-iter) ----
template<int CTRL, int ROWMASK>
__device__ __forceinline__ float dpp_add(float x) {
  int v = __builtin_amdgcn_update_dpp(0, __float_as_int(x), CTRL, ROWMASK, 0xf, true);
  return x + __int_as_float(v);
}

__device__ __forceinline__ float wave_sum(float x) {
  x = dpp_add<0xB1,  0xF>(x);
  x = dpp_add<0x4E,  0xF>(x);
  x = dpp_add<0x141, 0xF>(x);
  x = dpp_add<0x140, 0xF>(x);
  x = dpp_add<0x142, 0xA>(x);
  x = dpp_add<0x143, 0xC>(x);
  return __int_as_float(__builtin_amdgcn_readlane(__float_as_int(x), 63));
}

__device__ __forceinline__ float rl(float x, int k) {
  return __int_as_float(__builtin_amdgcn_readlane(__float_as_int(x), k));
}

// ---------- kernel A: column sums over V of seeds / exp_s / exp_n ----------
__global__ __launch_bounds__(256) void sums_kernel(
    const float* __restrict__ seeds, const float* __restrict__ es,
    const float* __restrict__ en, float* __restrict__ sums,
    int V, int rows_per_block) {
  __shared__ float sh[192];
  int t = threadIdx.x;
  if (t < 192) sh[t] = 0.f;
  __syncthreads();
  int k = t & 63, w = t >> 6;
  int v0 = blockIdx.x * rows_per_block;
  int v1 = min(v0 + rows_per_block, V);
  float s0 = 0.f, s1 = 0.f, s2 = 0.f;
  for (int v = v0 + w; v < v1; v += 4) {
    int idx = (v << 6) + k;
    s0 += seeds[idx]; s1 += es[idx]; s2 += en[idx];
  }
  atomicAdd(&sh[k], s0);
  atomicAdd(&sh[64 + k], s1);
  atomicAdd(&sh[128 + k], s2);
  __syncthreads();
  if (t < 192) atomicAdd(&sums[t], sh[t]);
}

// ---------- kernel B: main per-(v) wave kernel ----------
__global__ __launch_bounds__(1024) void main_kernel(
    const float* __restrict__ bow,   // (B=64, V)
    const float* __restrict__ seeds, // (V, 64)
    const float* __restrict__ exp_m, // (64, 64)
    const float* __restrict__ exp_s, // (V, 64)
    const float* __restrict__ exp_n, // (V, 64)
    const float* __restrict__ pi,    // (64)
    const float* __restrict__ sums,  // [S | exp_s_sum | exp_n_sum]
    float* __restrict__ out,
    float* __restrict__ wsm, float* __restrict__ wsg, float* __restrict__ wsq,
    int V, int useWs) {
  __shared__ float theta_lds[4096];       // theta[b*64+k]
  __shared__ float thetaT_lds[64 * 65];   // theta[k*65+b]  (padded)
  __shared__ float accm_lds[4096];        // temp_exp_m block partial
  __shared__ float2 inv_lds[16 * 64];     // per-wave (inv_s, inv_r) per b
  __shared__ float red_gsr[16 * 64];
  __shared__ float red_qz[16];

  int t = threadIdx.x;
#pragma unroll
  for (int i = 0; i < 4; i++) {
    int idx = t + i * 1024;
    float val = exp_m[idx] + ETA_C;
    theta_lds[idx] = val;
    thetaT_lds[(idx & 63) * 65 + (idx >> 6)] = val;
    accm_lds[idx] = 0.f;
  }
  __syncthreads();

  int lane = t & 63, w = t >> 6;
  int v = blockIdx.x * 16 + w;
  bool active = (v < V);

  float acc_n = 0.f, acc_s = 0.f, acc_g = 0.f, acc_q = 0.f;

  if (active) {
    int rbase = (v << 6) + lane;
    float seed = seeds[rbase];
    float es = exp_s[rbase];
    float en = exp_n[rbase];
    float pik = pi[lane];
    float Sk = sums[lane], essum = sums[64 + lane], ensum = sums[128 + lane];
    float inv_ds = __builtin_amdgcn_rcpf(MU_C * Sk + essum);
    float inv_dn = __builtin_amdgcn_rcpf(BETA_C * (float)V + ensum);
    float phi_s = (MU_C + es) * inv_ds;
    float phi_n = (BETA_C + en) * inv_dn;
    float omp = 1.0f - pik;
    float a_ss = seed * phi_s * pik;       // lane = k
    float a_sr = seed * phi_n * omp;
    float a_rr = (1.0f - seed) * phi_n;
    float asv = a_ss + a_sr;
    bool seedRow = (__ballot(seed > 0.f) != 0ull);

    float bowpre = bow[lane * V + v];      // lane = b
    unsigned long long m = __ballot(bowpre > 0.f);

    // ---- phase 1 (lane = b): matvec for s_sum / r_sum, no cross-lane ops ----
    float ss = 0.f, rs = 0.f;
    if (seedRow) {
#pragma unroll
      for (int k = 0; k < 64; k++) {
        float th = thetaT_lds[k * 65 + lane];
        ss = fmaf(th, rl(asv, k), ss);
        rs = fmaf(th, rl(a_rr, k), rs);
      }
    } else {
#pragma unroll
      for (int k = 0; k < 64; k++) {
        float th = thetaT_lds[k * 65 + lane];
        rs = fmaf(th, rl(a_rr, k), rs);
      }
    }
    // one rcp covers all 64 b's (lane = b)
    float2 iv;
    iv.x = __builtin_amdgcn_rcpf(ss + MINI_C);
    iv.y = __builtin_amdgcn_rcpf(rs + MINI_C);
    inv_lds[(w << 6) + lane] = iv;

    // ---- phase 2 (lane = k): per active b, straight-line, no reductions ----
    if (seedRow) {
      while (m) {
        int b = __builtin_ctzll(m);
        m &= (m - 1);
        float cb = rl(bowpre, b);
        float2 inv = inv_lds[(w << 6) + b];       // broadcast
        float th = theta_lds[(b << 6) + lane];
        float gss = th * a_ss * inv.x;
        float gsr = th * a_sr * inv.x;
        float grr = th * a_rr * inv.y;
        float gnr = gsr + grr;
        float gamma = fmaf(pik, gss, omp * gnr);
        acc_n = fmaf(gnr, cb, acc_n);
        acc_s = fmaf(gss, cb, acc_s);
        acc_g += gsr;
        acc_q = fmaf(gamma, __logf(gamma + MINI_C), acc_q);
        atomicAdd(&accm_lds[(b << 6) + lane], gamma * cb);
      }
    } else {
      while (m) {
        int b = __builtin_ctzll(m);
        m &= (m - 1);
        float cb = rl(bowpre, b);
        float2 inv = inv_lds[(w << 6) + b];       // broadcast
        float th = theta_lds[(b << 6) + lane];
        float grr = th * a_rr * inv.y;            // gamma == grr here
        float gc = grr * cb;
        acc_n += gc;
        acc_q = fmaf(grr, __logf(grr + MINI_C), acc_q);
        atomicAdd(&accm_lds[(b << 6) + lane], gc);
      }
    }

    out[4096 + rbase] = acc_n;            // temp_exp_n
    out[4096 + V * 64 + rbase] = acc_s;   // temp_exp_s
  }

  red_gsr[(w << 6) | lane] = acc_g;
  float qz_w = wave_sum(acc_q);
  if (lane == 0) red_qz[w] = qz_w;
  __syncthreads();

  // flush temp_exp_m block partial
  if (useWs) {
#pragma unroll
    for (int i = 0; i < 4; i++)
      wsm[blockIdx.x * 4096 + t + i * 1024] = accm_lds[t + i * 1024];
  } else {
#pragma unroll
    for (int i = 0; i < 4; i++)
      atomicAdd(&out[t + i * 1024], accm_lds[t + i * 1024]);
  }

  if (w == 0) {
    int gsr_off = 4096 + 2 * V * 64;
    float g = 0.f;
#pragma unroll
    for (int j = 0; j < 16; j++) g += red_gsr[(j << 6) | lane];
    if (useWs) wsg[blockIdx.x * 64 + lane] = g;
    else atomicAdd(&out[gsr_off + lane], g);
    if (t == 0) {
      float q = 0.f;
#pragma unroll
      for (int j = 0; j < 16; j++) q += red_qz[j];
      if (useWs) wsq[blockIdx.x] = q;
      else atomicAdd(&out[gsr_off + 64], q);
    }
  }
}

// ---------- kernel C: reduce per-block partials ----------
__global__ __launch_bounds__(256) void reduce_kernel(
    const float* __restrict__ wsm, const float* __restrict__ wsg,
    const float* __restrict__ wsq, float* __restrict__ out,
    int NB, int V, int chunk) {
  if (blockIdx.x < 16) {
    int e = blockIdx.x * 256 + threadIdx.x;
    int j0 = blockIdx.y * chunk;
    int j1 = min(j0 + chunk, NB);
    float s = 0.f;
    for (int j = j0; j < j1; j++) s += wsm[j * 4096 + e];
    atomicAdd(&out[e], s);
  } else if (blockIdx.y == 0) {
    int t = threadIdx.x;
    int gsr_off = 4096 + 2 * V * 64;
    if (t < 64) {
      float s = 0.f;
      for (int j = 0; j < NB; j++) s += wsg[j * 64 + t];
      out[gsr_off + t] = s;
    } else if (t < 128) {
      int lane = t - 64;
      float s = 0.f;
      for (int j = lane; j < NB; j += 64) s += wsq[j];
      s = wave_sum(s);
      if (lane == 0) out[gsr_off + 64] = s;
    }
  }
}

extern "C" void kernel_launch(void* const* d_in, const int* in_sizes, int n_in,
                              void* d_out, int out_size, void* d_ws,
                              size_t ws_size, hipStream_t stream) {
  (void)n_in;
  const float* bow   = (const float*)d_in[0];
  const float* seeds = (const float*)d_in[1];
  const float* exp_m = (const float*)d_in[2];
  const float* exp_s = (const float*)d_in[3];
  const float* exp_n = (const float*)d_in[4];
  const float* pi    = (const float*)d_in[5];
  int K = in_sizes[5];          // 64
  int V = in_sizes[1] / K;      // 10000
  float* out = (float*)d_out;
  float* ws = (float*)d_ws;

  int NB = (V + 15) / 16;       // 625 blocks, 16 waves (one v each) per block
  size_t need = (size_t)(256 + (size_t)NB * 4096 + (size_t)NB * 64 + NB) * 4;
  int useWs = (ws_size >= need) ? 1 : 0;

  float* sums = ws;             // 192 floats (+pad)
  float* wsm = ws + 256;        // NB x 4096
  float* wsg = wsm + (size_t)NB * 4096;  // NB x 64
  float* wsq = wsg + (size_t)NB * 64;    // NB

  hipMemsetAsync(d_out, 0, (size_t)out_size * sizeof(float), stream);
  hipMemsetAsync(d_ws, 0, 768, stream);

  int rpb = (V + 99) / 100;
  sums_kernel<<<100, 256, 0, stream>>>(seeds, exp_s, exp_n, sums, V, rpb);
  main_kernel<<<NB, 1024, 0, stream>>>(bow, seeds, exp_m, exp_s, exp_n, pi,
                                       sums, out, wsm, wsg, wsq, V, useWs);
  if (useWs) {
    int chunk = (NB + 4) / 5;
    reduce_kernel<<<dim3(17, 5), 256, 0, stream>>>(wsm, wsg, wsq, out, NB, V,
                                                   chunk);
  }
}

// Round 3
// 335.361 us; speedup vs baseline: 1.2521x; 1.2521x over previous
//
#include <hip/hip_runtime.h>
#include <hip/hip_bf16.h>

#define ETA_C  0.1f
#define BETA_C 0.05f
#define MU_C   0.05f
#define MINI_C 1e-6f

// ---------- DPP wave-64 sum ----------
template<int CTRL, int ROWMASK>
__device__ __forceinline__ float dpp_add(float x) {
  int v = __builtin_amdgcn_update_dpp(0, __float_as_int(x), CTRL, ROWMASK, 0xf, true);
  return x + __int_as_float(v);
}

__device__ __forceinline__ float wave_sum(float x) {
  x = dpp_add<0xB1,  0xF>(x);
  x = dpp_add<0x4E,  0xF>(x);
  x = dpp_add<0x141, 0xF>(x);
  x = dpp_add<0x140, 0xF>(x);
  x = dpp_add<0x142, 0xA>(x);
  x = dpp_add<0x143, 0xC>(x);
  return __int_as_float(__builtin_amdgcn_readlane(__float_as_int(x), 63));
}

__device__ __forceinline__ float rl(float x, int k) {
  return __int_as_float(__builtin_amdgcn_readlane(__float_as_int(x), k));
}

// ---------- kernel A: column sums over V of seeds / exp_s / exp_n ----------
__global__ __launch_bounds__(256) void sums_kernel(
    const float* __restrict__ seeds, const float* __restrict__ es,
    const float* __restrict__ en, float* __restrict__ sums,
    int V, int rows_per_block) {
  __shared__ float sh[192];
  int t = threadIdx.x;
  if (t < 192) sh[t] = 0.f;
  __syncthreads();
  int k = t & 63, w = t >> 6;
  int v0 = blockIdx.x * rows_per_block;
  int v1 = min(v0 + rows_per_block, V);
  float s0 = 0.f, s1 = 0.f, s2 = 0.f;
  for (int v = v0 + w; v < v1; v += 4) {
    int idx = (v << 6) + k;
    s0 += seeds[idx]; s1 += es[idx]; s2 += en[idx];
  }
  atomicAdd(&sh[k], s0);
  atomicAdd(&sh[64 + k], s1);
  atomicAdd(&sh[128 + k], s2);
  __syncthreads();
  if (t < 192) atomicAdd(&sums[t], sh[t]);
}

// ---------- kernel B: main per-(v) wave kernel — NO LDS atomics ----------
__global__ __launch_bounds__(1024) void main_kernel(
    const float* __restrict__ bow,   // (B=64, V)
    const float* __restrict__ seeds, // (V, 64)
    const float* __restrict__ exp_m, // (64, 64)
    const float* __restrict__ exp_s, // (V, 64)
    const float* __restrict__ exp_n, // (V, 64)
    const float* __restrict__ pi,    // (64)
    const float* __restrict__ sums,  // [S | exp_s_sum | exp_n_sum]
    float* __restrict__ out,
    float* __restrict__ wsm, float* __restrict__ wsg, float* __restrict__ wsq,
    int V, int useWs) {
  __shared__ float theta_lds[4096];       // theta[b*64+k]
  __shared__ float thetaT_lds[64 * 65];   // theta[k*65+b]  (padded)
  __shared__ float wsL[1024];             // per-wave w_s[v,k]   (lane=k)
  __shared__ float wrL[1024];             // per-wave w_r[v,k]   (lane=k)
  __shared__ float cisL[1024];            // per-wave c*inv_s[b] (lane=b)
  __shared__ float cirL[1024];            // per-wave c*inv_r[b] (lane=b)
  __shared__ float red_gsr[1024];
  __shared__ float red_qz[16];

  int t = threadIdx.x;
#pragma unroll
  for (int i = 0; i < 4; i++) {
    int idx = t + i * 1024;
    float val = exp_m[idx] + ETA_C;
    theta_lds[idx] = val;
    thetaT_lds[(idx & 63) * 65 + (idx >> 6)] = val;
  }
  __syncthreads();

  int lane = t & 63, w = t >> 6;
  int v = blockIdx.x * 16 + w;
  bool active = (v < V);

  float acc_n = 0.f, acc_s = 0.f, acc_g = 0.f, acc_q = 0.f;
  float ivx = 0.f, ivy = 0.f, bowpre = 0.f;
  float a_ss = 0.f, a_sr = 0.f, a_rr = 0.f, pik = 0.f, omp = 0.f;
  unsigned long long m = 0ull;
  bool seedRow = false;

  if (active) {
    int rbase = (v << 6) + lane;
    float seed = seeds[rbase];
    float es = exp_s[rbase];
    float en = exp_n[rbase];
    pik = pi[lane];
    float Sk = sums[lane], essum = sums[64 + lane], ensum = sums[128 + lane];
    float inv_ds = __builtin_amdgcn_rcpf(MU_C * Sk + essum);
    float inv_dn = __builtin_amdgcn_rcpf(BETA_C * (float)V + ensum);
    float phi_s = (MU_C + es) * inv_ds;
    float phi_n = (BETA_C + en) * inv_dn;
    omp = 1.0f - pik;
    a_ss = seed * phi_s * pik;            // lane = k
    a_sr = seed * phi_n * omp;
    a_rr = (1.0f - seed) * phi_n;
    seedRow = (__ballot(seed > 0.f) != 0ull);

    // stage GEMM weights (plain LDS writes)
    wsL[(w << 6) + lane] = fmaf(pik, a_ss, omp * a_sr);
    wrL[(w << 6) + lane] = seedRow ? omp * a_rr : a_rr;

    bowpre = bow[lane * V + v];           // lane = b
    m = __ballot(bowpre > 0.f);

    // ---- phase 1 (lane = b): matvec for s_sum / r_sum ----
    float asv = a_ss + a_sr;
    float ss = 0.f, rs = 0.f;
    if (seedRow) {
#pragma unroll
      for (int k = 0; k < 64; k++) {
        float th = thetaT_lds[k * 65 + lane];
        ss = fmaf(th, rl(asv, k), ss);
        rs = fmaf(th, rl(a_rr, k), rs);
      }
    } else {
#pragma unroll
      for (int k = 0; k < 64; k++) {
        float th = thetaT_lds[k * 65 + lane];
        rs = fmaf(th, rl(a_rr, k), rs);
      }
    }
    ivx = __builtin_amdgcn_rcpf(ss + MINI_C);
    ivy = __builtin_amdgcn_rcpf(rs + MINI_C);
    cisL[(w << 6) + lane] = bowpre * ivx;   // zero for inactive (b,v)
    cirL[(w << 6) + lane] = bowpre * ivy;
  } else {
    wsL[(w << 6) + lane] = 0.f;
    wrL[(w << 6) + lane] = 0.f;
    cisL[(w << 6) + lane] = 0.f;
    cirL[(w << 6) + lane] = 0.f;
  }
  __syncthreads();

  // ---- phase 2 (lane = k): per active b, register-only accumulation ----
  if (active) {
    int rbase = (v << 6) + lane;
    if (seedRow) {
      while (m) {
        int b = __builtin_ctzll(m);
        m &= (m - 1);
        float cb = rl(bowpre, b);
        float is = rl(ivx, b), ir = rl(ivy, b);
        float th = theta_lds[(b << 6) + lane];
        float gss = th * a_ss * is;
        float gsr = th * a_sr * is;
        float grr = th * a_rr * ir;
        float gnr = gsr + grr;
        float gamma = fmaf(pik, gss, omp * gnr);
        acc_n = fmaf(gnr, cb, acc_n);
        acc_s = fmaf(gss, cb, acc_s);
        acc_g += gsr;
        acc_q = fmaf(gamma, __logf(gamma + MINI_C), acc_q);
      }
    } else {
      while (m) {
        int b = __builtin_ctzll(m);
        m &= (m - 1);
        float cb = rl(bowpre, b);
        float ir = rl(ivy, b);
        float th = theta_lds[(b << 6) + lane];
        float grr = th * a_rr * ir;           // gamma == grr
        acc_n = fmaf(grr, cb, acc_n);
        acc_q = fmaf(grr, __logf(grr + MINI_C), acc_q);
      }
    }
    out[4096 + rbase] = acc_n;            // temp_exp_n
    out[4096 + V * 64 + rbase] = acc_s;   // temp_exp_s
  }

  // ---- phase 2b (lane = k): block outer-product partial for temp_exp_m ----
  // P[b,k] = sum_u cis[u][b]*ws[u][k] + cir[u][b]*wr[u][k];  wave w owns b=4w..4w+3
  {
    float acc4x = 0.f, acc4y = 0.f, acc4z = 0.f, acc4w = 0.f;
#pragma unroll
    for (int u = 0; u < 16; u++) {
      float wsu = wsL[(u << 6) + lane];
      float wru = wrL[(u << 6) + lane];
      float4 c4 = *(const float4*)&cisL[(u << 6) + (w << 2)];  // broadcast b128
      float4 r4 = *(const float4*)&cirL[(u << 6) + (w << 2)];
      acc4x = fmaf(c4.x, wsu, fmaf(r4.x, wru, acc4x));
      acc4y = fmaf(c4.y, wsu, fmaf(r4.y, wru, acc4y));
      acc4z = fmaf(c4.z, wsu, fmaf(r4.z, wru, acc4z));
      acc4w = fmaf(c4.w, wsu, fmaf(r4.w, wru, acc4w));
    }
    float av[4] = {acc4x, acc4y, acc4z, acc4w};
#pragma unroll
    for (int j = 0; j < 4; j++) {
      int b = (w << 2) + j;
      float val = av[j] * theta_lds[(b << 6) + lane];  // theta multiply (distributive)
      if (useWs) wsm[blockIdx.x * 4096 + (b << 6) + lane] = val;
      else atomicAdd(&out[(b << 6) + lane], val);
    }
  }

  red_gsr[(w << 6) | lane] = acc_g;
  float qz_w = wave_sum(acc_q);
  if (lane == 0) red_qz[w] = qz_w;
  __syncthreads();

  if (w == 0) {
    int gsr_off = 4096 + 2 * V * 64;
    float g = 0.f;
#pragma unroll
    for (int j = 0; j < 16; j++) g += red_gsr[(j << 6) | lane];
    if (useWs) wsg[blockIdx.x * 64 + lane] = g;
    else atomicAdd(&out[gsr_off + lane], g);
    if (t == 0) {
      float q = 0.f;
#pragma unroll
      for (int j = 0; j < 16; j++) q += red_qz[j];
      if (useWs) wsq[blockIdx.x] = q;
      else atomicAdd(&out[gsr_off + 64], q);
    }
  }
}

// ---------- kernel C: reduce per-block partials ----------
__global__ __launch_bounds__(256) void reduce_kernel(
    const float* __restrict__ wsm, const float* __restrict__ wsg,
    const float* __restrict__ wsq, float* __restrict__ out,
    int NB, int V, int chunk) {
  if (blockIdx.x < 16) {
    int e = blockIdx.x * 256 + threadIdx.x;
    int j0 = blockIdx.y * chunk;
    int j1 = min(j0 + chunk, NB);
    float s = 0.f;
    for (int j = j0; j < j1; j++) s += wsm[j * 4096 + e];
    atomicAdd(&out[e], s);
  } else if (blockIdx.y == 0) {
    int t = threadIdx.x;
    int gsr_off = 4096 + 2 * V * 64;
    if (t < 64) {
      float s = 0.f;
      for (int j = 0; j < NB; j++) s += wsg[j * 64 + t];
      out[gsr_off + t] = s;
    } else if (t < 128) {
      int lane = t - 64;
      float s = 0.f;
      for (int j = lane; j < NB; j += 64) s += wsq[j];
      s = wave_sum(s);
      if (lane == 0) out[gsr_off + 64] = s;
    }
  }
}

extern "C" void kernel_launch(void* const* d_in, const int* in_sizes, int n_in,
                              void* d_out, int out_size, void* d_ws,
                              size_t ws_size, hipStream_t stream) {
  (void)n_in;
  const float* bow   = (const float*)d_in[0];
  const float* seeds = (const float*)d_in[1];
  const float* exp_m = (const float*)d_in[2];
  const float* exp_s = (const float*)d_in[3];
  const float* exp_n = (const float*)d_in[4];
  const float* pi    = (const float*)d_in[5];
  int K = in_sizes[5];          // 64
  int V = in_sizes[1] / K;      // 10000
  float* out = (float*)d_out;
  float* ws = (float*)d_ws;

  int NB = (V + 15) / 16;       // 625 blocks, 16 waves (one v each) per block
  size_t need = (size_t)(256 + (size_t)NB * 4096 + (size_t)NB * 64 + NB) * 4;
  int useWs = (ws_size >= need) ? 1 : 0;

  float* sums = ws;             // 192 floats (+pad)
  float* wsm = ws + 256;        // NB x 4096
  float* wsg = wsm + (size_t)NB * 4096;  // NB x 64
  float* wsq = wsg + (size_t)NB * 64;    // NB

  hipMemsetAsync(d_out, 0, (size_t)out_size * sizeof(float), stream);
  hipMemsetAsync(d_ws, 0, 768, stream);

  int rpb = (V + 99) / 100;
  sums_kernel<<<100, 256, 0, stream>>>(seeds, exp_s, exp_n, sums, V, rpb);
  main_kernel<<<NB, 1024, 0, stream>>>(bow, seeds, exp_m, exp_s, exp_n, pi,
                                       sums, out, wsm, wsg, wsq, V, useWs);
  if (useWs) {
    int chunk = (NB + 4) / 5;
    reduce_kernel<<<dim3(17, 5), 256, 0, stream>>>(wsm, wsg, wsq, out, NB, V,
                                                   chunk);
  }
}

// Round 4
// 194.023 us; speedup vs baseline: 2.1642x; 1.7285x over previous
//
#include <hip/hip_runtime.h>
#include <hip/hip_bf16.h>

#define ETA_C  0.1f
#define BETA_C 0.05f
#define MU_C   0.05f
#define MINI_C 1e-6f

// ---------- DPP wave-64 sum ----------
template<int CTRL, int ROWMASK>
__device__ __forceinline__ float dpp_add(float x) {
  int v = __builtin_amdgcn_update_dpp(0, __float_as_int(x), CTRL, ROWMASK, 0xf, true);
  return x + __int_as_float(v);
}

__device__ __forceinline__ float wave_sum(float x) {
  x = dpp_add<0xB1,  0xF>(x);
  x = dpp_add<0x4E,  0xF>(x);
  x = dpp_add<0x141, 0xF>(x);
  x = dpp_add<0x140, 0xF>(x);
  x = dpp_add<0x142, 0xA>(x);
  x = dpp_add<0x143, 0xC>(x);
  return __int_as_float(__builtin_amdgcn_readlane(__float_as_int(x), 63));
}

__device__ __forceinline__ float rl(float x, int k) {
  return __int_as_float(__builtin_amdgcn_readlane(__float_as_int(x), k));
}

// ---------- kernel A: column sums over V of seeds / exp_s / exp_n ----------
__global__ __launch_bounds__(256) void sums_kernel(
    const float* __restrict__ seeds, const float* __restrict__ es,
    const float* __restrict__ en, float* __restrict__ sums,
    int V, int rows_per_block) {
  __shared__ float sh[192];
  int t = threadIdx.x;
  if (t < 192) sh[t] = 0.f;
  __syncthreads();
  int k = t & 63, w = t >> 6;
  int v0 = blockIdx.x * rows_per_block;
  int v1 = min(v0 + rows_per_block, V);
  float s0 = 0.f, s1 = 0.f, s2 = 0.f;
  for (int v = v0 + w; v < v1; v += 4) {
    int idx = (v << 6) + k;
    s0 += seeds[idx]; s1 += es[idx]; s2 += en[idx];
  }
  atomicAdd(&sh[k], s0);
  atomicAdd(&sh[64 + k], s1);
  atomicAdd(&sh[128 + k], s2);
  __syncthreads();
  if (t < 192) atomicAdd(&sums[t], sh[t]);
}

// ---------- kernel B: main per-(v) wave kernel — NO LDS atomics ----------
__global__ __launch_bounds__(1024) void main_kernel(
    const float* __restrict__ bow,   // (B=64, V)
    const float* __restrict__ seeds, // (V, 64)
    const float* __restrict__ exp_m, // (64, 64)
    const float* __restrict__ exp_s, // (V, 64)
    const float* __restrict__ exp_n, // (V, 64)
    const float* __restrict__ pi,    // (64)
    const float* __restrict__ sums,  // [S | exp_s_sum | exp_n_sum]
    float* __restrict__ out,
    float* __restrict__ wsm, float* __restrict__ wsg, float* __restrict__ wsq,
    int V, int useWs) {
  __shared__ float theta_lds[4096];       // theta[b*64+k]
  __shared__ float thetaT_lds[64 * 65];   // theta[k*65+b]  (padded)
  __shared__ float wsL[1024];             // per-wave w_s[v,k]   (lane=k)
  __shared__ float wrL[1024];             // per-wave w_r[v,k]   (lane=k)
  __shared__ float cisL[1024];            // per-wave c*inv_s[b] (lane=b)
  __shared__ float cirL[1024];            // per-wave c*inv_r[b] (lane=b)
  __shared__ float red_gsr[1024];
  __shared__ float red_qz[16];

  int t = threadIdx.x;
#pragma unroll
  for (int i = 0; i < 4; i++) {
    int idx = t + i * 1024;
    float val = exp_m[idx] + ETA_C;
    theta_lds[idx] = val;
    thetaT_lds[(idx & 63) * 65 + (idx >> 6)] = val;
  }
  __syncthreads();

  int lane = t & 63, w = t >> 6;
  int v = blockIdx.x * 16 + w;
  bool active = (v < V);

  float acc_n = 0.f, acc_s = 0.f, acc_g = 0.f, acc_q = 0.f;
  float ivx = 0.f, ivy = 0.f, bowpre = 0.f;
  float a_ss = 0.f, a_sr = 0.f, a_rr = 0.f, pik = 0.f, omp = 0.f;
  unsigned long long m = 0ull;
  bool seedRow = false;

  if (active) {
    int rbase = (v << 6) + lane;
    float seed = seeds[rbase];
    float es = exp_s[rbase];
    float en = exp_n[rbase];
    pik = pi[lane];
    float Sk = sums[lane], essum = sums[64 + lane], ensum = sums[128 + lane];
    float inv_ds = __builtin_amdgcn_rcpf(MU_C * Sk + essum);
    float inv_dn = __builtin_amdgcn_rcpf(BETA_C * (float)V + ensum);
    float phi_s = (MU_C + es) * inv_ds;
    float phi_n = (BETA_C + en) * inv_dn;
    omp = 1.0f - pik;
    a_ss = seed * phi_s * pik;            // lane = k
    a_sr = seed * phi_n * omp;
    a_rr = (1.0f - seed) * phi_n;
    seedRow = (__ballot(seed > 0.f) != 0ull);

    // stage GEMM weights (plain LDS writes)
    wsL[(w << 6) + lane] = fmaf(pik, a_ss, omp * a_sr);
    wrL[(w << 6) + lane] = seedRow ? omp * a_rr : a_rr;

    bowpre = bow[lane * V + v];           // lane = b
    m = __ballot(bowpre > 0.f);

    // ---- phase 1 (lane = b): matvec for s_sum / r_sum ----
    float asv = a_ss + a_sr;
    float ss = 0.f, rs = 0.f;
    if (seedRow) {
#pragma unroll
      for (int k = 0; k < 64; k++) {
        float th = thetaT_lds[k * 65 + lane];
        ss = fmaf(th, rl(asv, k), ss);
        rs = fmaf(th, rl(a_rr, k), rs);
      }
    } else {
#pragma unroll
      for (int k = 0; k < 64; k++) {
        float th = thetaT_lds[k * 65 + lane];
        rs = fmaf(th, rl(a_rr, k), rs);
      }
    }
    ivx = __builtin_amdgcn_rcpf(ss + MINI_C);
    ivy = __builtin_amdgcn_rcpf(rs + MINI_C);
    cisL[(w << 6) + lane] = bowpre * ivx;   // zero for inactive (b,v)
    cirL[(w << 6) + lane] = bowpre * ivy;
  } else {
    wsL[(w << 6) + lane] = 0.f;
    wrL[(w << 6) + lane] = 0.f;
    cisL[(w << 6) + lane] = 0.f;
    cirL[(w << 6) + lane] = 0.f;
  }
  __syncthreads();

  // ---- phase 2 (lane = k): per active b, register-only accumulation ----
  if (active) {
    int rbase = (v << 6) + lane;
    if (seedRow) {
      while (m) {
        int b = __builtin_ctzll(m);
        m &= (m - 1);
        float cb = rl(bowpre, b);
        float is = rl(ivx, b), ir = rl(ivy, b);
        float th = theta_lds[(b << 6) + lane];
        float gss = th * a_ss * is;
        float gsr = th * a_sr * is;
        float grr = th * a_rr * ir;
        float gnr = gsr + grr;
        float gamma = fmaf(pik, gss, omp * gnr);
        acc_n = fmaf(gnr, cb, acc_n);
        acc_s = fmaf(gss, cb, acc_s);
        acc_g += gsr;
        acc_q = fmaf(gamma, __logf(gamma + MINI_C), acc_q);
      }
    } else {
      while (m) {
        int b = __builtin_ctzll(m);
        m &= (m - 1);
        float cb = rl(bowpre, b);
        float ir = rl(ivy, b);
        float th = theta_lds[(b << 6) + lane];
        float grr = th * a_rr * ir;           // gamma == grr
        acc_n = fmaf(grr, cb, acc_n);
        acc_q = fmaf(grr, __logf(grr + MINI_C), acc_q);
      }
    }
    out[4096 + rbase] = acc_n;            // temp_exp_n
    out[4096 + V * 64 + rbase] = acc_s;   // temp_exp_s
  }

  // ---- phase 2b (lane = k): block outer-product partial for temp_exp_m ----
  // P[b,k] = sum_u cis[u][b]*ws[u][k] + cir[u][b]*wr[u][k];  wave w owns b=4w..4w+3
  {
    float acc4x = 0.f, acc4y = 0.f, acc4z = 0.f, acc4w = 0.f;
#pragma unroll
    for (int u = 0; u < 16; u++) {
      float wsu = wsL[(u << 6) + lane];
      float wru = wrL[(u << 6) + lane];
      float4 c4 = *(const float4*)&cisL[(u << 6) + (w << 2)];  // broadcast b128
      float4 r4 = *(const float4*)&cirL[(u << 6) + (w << 2)];
      acc4x = fmaf(c4.x, wsu, fmaf(r4.x, wru, acc4x));
      acc4y = fmaf(c4.y, wsu, fmaf(r4.y, wru, acc4y));
      acc4z = fmaf(c4.z, wsu, fmaf(r4.z, wru, acc4z));
      acc4w = fmaf(c4.w, wsu, fmaf(r4.w, wru, acc4w));
    }
    float av[4] = {acc4x, acc4y, acc4z, acc4w};
#pragma unroll
    for (int j = 0; j < 4; j++) {
      int b = (w << 2) + j;
      float val = av[j] * theta_lds[(b << 6) + lane];  // theta multiply (distributive)
      if (useWs) wsm[blockIdx.x * 4096 + (b << 6) + lane] = val;
      else atomicAdd(&out[(b << 6) + lane], val);
    }
  }

  red_gsr[(w << 6) | lane] = acc_g;
  float qz_w = wave_sum(acc_q);
  if (lane == 0) red_qz[w] = qz_w;
  __syncthreads();

  if (w == 0) {
    int gsr_off = 4096 + 2 * V * 64;
    float g = 0.f;
#pragma unroll
    for (int j = 0; j < 16; j++) g += red_gsr[(j << 6) | lane];
    if (useWs) wsg[blockIdx.x * 64 + lane] = g;
    else atomicAdd(&out[gsr_off + lane], g);
    if (t == 0) {
      float q = 0.f;
#pragma unroll
      for (int j = 0; j < 16; j++) q += red_qz[j];
      if (useWs) wsq[blockIdx.x] = q;
      else atomicAdd(&out[gsr_off + 64], q);
    }
  }
}

// ---------- kernel C: parallel reduce of per-block partials ----------
// grid = 66 blocks x 1024 threads.
//   blocks 0..63 : temp_exp_m — block bx owns 64 elements e=bx*64+lane,
//                  16-way j-split across waves, x4 unrolled independent chains
//   block 64     : gamma_sr_sum (625 x 64)
//   block 65     : exp_q_z (625)
__global__ __launch_bounds__(1024) void reduce_kernel(
    const float* __restrict__ wsm, const float* __restrict__ wsg,
    const float* __restrict__ wsq, float* __restrict__ out,
    int NB, int V) {
  __shared__ float sh[1024];
  int t = threadIdx.x;
  int lane = t & 63, w = t >> 6;
  int bx = blockIdx.x;
  int gsr_off = 4096 + 2 * V * 64;

  if (bx < 64) {
    int e = (bx << 6) + lane;
    float s0 = 0.f, s1 = 0.f, s2 = 0.f, s3 = 0.f;
    int j = w;
    for (; j + 48 < NB; j += 64) {
      s0 += wsm[(size_t)(j)      * 4096 + e];
      s1 += wsm[(size_t)(j + 16) * 4096 + e];
      s2 += wsm[(size_t)(j + 32) * 4096 + e];
      s3 += wsm[(size_t)(j + 48) * 4096 + e];
    }
    for (; j < NB; j += 16) s0 += wsm[(size_t)j * 4096 + e];
    sh[t] = (s0 + s1) + (s2 + s3);
    __syncthreads();
    if (w == 0) {
      float tot = 0.f;
#pragma unroll
      for (int i = 0; i < 16; i++) tot += sh[(i << 6) + lane];
      out[e] = tot;   // out[0..4095] pre-zeroed; single writer per e
    }
  } else if (bx == 64) {
    float s0 = 0.f, s1 = 0.f;
    int j = w;
    for (; j + 16 < NB; j += 32) {
      s0 += wsg[((j) << 6) + lane];
      s1 += wsg[((j + 16) << 6) + lane];
    }
    for (; j < NB; j += 16) s0 += wsg[(j << 6) + lane];
    sh[t] = s0 + s1;
    __syncthreads();
    if (w == 0) {
      float tot = 0.f;
#pragma unroll
      for (int i = 0; i < 16; i++) tot += sh[(i << 6) + lane];
      out[gsr_off + lane] = tot;
    }
  } else {
    float s = 0.f;
    for (int j = t; j < NB; j += 1024) s += wsq[j];
    s = wave_sum(s);
    if (lane == 0) sh[w] = s;
    __syncthreads();
    if (t == 0) {
      float tot = 0.f;
#pragma unroll
      for (int i = 0; i < 16; i++) tot += sh[i];
      out[gsr_off + 64] = tot;
    }
  }
}

extern "C" void kernel_launch(void* const* d_in, const int* in_sizes, int n_in,
                              void* d_out, int out_size, void* d_ws,
                              size_t ws_size, hipStream_t stream) {
  (void)n_in;
  const float* bow   = (const float*)d_in[0];
  const float* seeds = (const float*)d_in[1];
  const float* exp_m = (const float*)d_in[2];
  const float* exp_s = (const float*)d_in[3];
  const float* exp_n = (const float*)d_in[4];
  const float* pi    = (const float*)d_in[5];
  int K = in_sizes[5];          // 64
  int V = in_sizes[1] / K;      // 10000
  float* out = (float*)d_out;
  float* ws = (float*)d_ws;

  int NB = (V + 15) / 16;       // 625 blocks, 16 waves (one v each) per block
  size_t need = (size_t)(256 + (size_t)NB * 4096 + (size_t)NB * 64 + NB) * 4;
  int useWs = (ws_size >= need) ? 1 : 0;

  float* sums = ws;             // 192 floats (+pad)
  float* wsm = ws + 256;        // NB x 4096
  float* wsg = wsm + (size_t)NB * 4096;  // NB x 64
  float* wsq = wsg + (size_t)NB * 64;    // NB

  hipMemsetAsync(d_out, 0, (size_t)out_size * sizeof(float), stream);
  hipMemsetAsync(d_ws, 0, 768, stream);

  int rpb = (V + 99) / 100;
  sums_kernel<<<100, 256, 0, stream>>>(seeds, exp_s, exp_n, sums, V, rpb);
  main_kernel<<<NB, 1024, 0, stream>>>(bow, seeds, exp_m, exp_s, exp_n, pi,
                                       sums, out, wsm, wsg, wsq, V, useWs);
  if (useWs) {
    reduce_kernel<<<66, 1024, 0, stream>>>(wsm, wsg, wsq, out, NB, V);
  }
}

// Round 5
// 134.657 us; speedup vs baseline: 3.1184x; 1.4409x over previous
//
#include <hip/hip_runtime.h>
#include <hip/hip_bf16.h>

#define ETA_C  0.1f
#define BETA_C 0.05f
#define MU_C   0.05f
#define MINI_C 1e-6f

// ---------- DPP wave-64 sum ----------
template<int CTRL, int ROWMASK>
__device__ __forceinline__ float dpp_add(float x) {
  int v = __builtin_amdgcn_update_dpp(0, __float_as_int(x), CTRL, ROWMASK, 0xf, true);
  return x + __int_as_float(v);
}

__device__ __forceinline__ float wave_sum(float x) {
  x = dpp_add<0xB1,  0xF>(x);
  x = dpp_add<0x4E,  0xF>(x);
  x = dpp_add<0x141, 0xF>(x);
  x = dpp_add<0x140, 0xF>(x);
  x = dpp_add<0x142, 0xA>(x);
  x = dpp_add<0x143, 0xC>(x);
  return __int_as_float(__builtin_amdgcn_readlane(__float_as_int(x), 63));
}

__device__ __forceinline__ float rl(float x, int k) {
  return __int_as_float(__builtin_amdgcn_readlane(__float_as_int(x), k));
}

// ---------- kernel A: column sums over V of seeds / exp_s / exp_n ----------
__global__ __launch_bounds__(256) void sums_kernel(
    const float* __restrict__ seeds, const float* __restrict__ es,
    const float* __restrict__ en, float* __restrict__ sums,
    int V, int rows_per_block) {
  __shared__ float sh[192];
  int t = threadIdx.x;
  if (t < 192) sh[t] = 0.f;
  __syncthreads();
  int k = t & 63, w = t >> 6;
  int v0 = blockIdx.x * rows_per_block;
  int v1 = min(v0 + rows_per_block, V);
  float s0 = 0.f, s1 = 0.f, s2 = 0.f;
  for (int v = v0 + w; v < v1; v += 4) {
    int idx = (v << 6) + k;
    s0 += seeds[idx]; s1 += es[idx]; s2 += en[idx];
  }
  atomicAdd(&sh[k], s0);
  atomicAdd(&sh[64 + k], s1);
  atomicAdd(&sh[128 + k], s2);
  __syncthreads();
  if (t < 192) atomicAdd(&sums[t], sh[t]);
}

// ---------- kernel B: main per-(v) wave kernel ----------
// __launch_bounds__(1024, 4): 4 waves/EU min -> VGPR cap 128, avoids the
// 64-VGPR cap + scratch spills seen in R4 (FETCH/WRITE blew up 20x).
__global__ __launch_bounds__(1024, 4) void main_kernel(
    const float* __restrict__ bow,   // (B=64, V)
    const float* __restrict__ seeds, // (V, 64)
    const float* __restrict__ exp_m, // (64, 64)
    const float* __restrict__ exp_s, // (V, 64)
    const float* __restrict__ exp_n, // (V, 64)
    const float* __restrict__ pi,    // (64)
    const float* __restrict__ sums,  // [S | exp_s_sum | exp_n_sum]
    float* __restrict__ out,
    float* __restrict__ wsm, float* __restrict__ wsg, float* __restrict__ wsq,
    int V, int useWs) {
  __shared__ float theta_lds[4096];       // theta[b*64+k]
  __shared__ float thetaT_lds[64 * 65];   // theta[k*65+b]  (padded)
  __shared__ float wsL[1024];             // per-wave w_s[v,k]   (lane=k)
  __shared__ float wrL[1024];             // per-wave w_r[v,k]   (lane=k)
  __shared__ float cisL[1024];            // per-wave c*inv_s[b] (lane=b)
  __shared__ float cirL[1024];            // per-wave c*inv_r[b] (lane=b)
  __shared__ float red_gsr[1024];
  __shared__ float red_qz[16];

  int t = threadIdx.x;
#pragma unroll
  for (int i = 0; i < 4; i++) {
    int idx = t + i * 1024;
    float val = exp_m[idx] + ETA_C;
    theta_lds[idx] = val;
    thetaT_lds[(idx & 63) * 65 + (idx >> 6)] = val;
  }
  __syncthreads();

  int lane = t & 63, w = t >> 6;
  int v = blockIdx.x * 16 + w;
  bool active = (v < V);

  float acc_n = 0.f, acc_s = 0.f, acc_g = 0.f, acc_q = 0.f;
  float ivx = 0.f, ivy = 0.f, bowpre = 0.f;
  float a_ss = 0.f, a_sr = 0.f, a_rr = 0.f, pik = 0.f, omp = 0.f;
  unsigned long long m = 0ull;
  bool seedRow = false;

  if (active) {
    int rbase = (v << 6) + lane;
    float seed = seeds[rbase];
    float es = exp_s[rbase];
    float en = exp_n[rbase];
    pik = pi[lane];
    float Sk = sums[lane], essum = sums[64 + lane], ensum = sums[128 + lane];
    float inv_ds = __builtin_amdgcn_rcpf(MU_C * Sk + essum);
    float inv_dn = __builtin_amdgcn_rcpf(BETA_C * (float)V + ensum);
    float phi_s = (MU_C + es) * inv_ds;
    float phi_n = (BETA_C + en) * inv_dn;
    omp = 1.0f - pik;
    a_ss = seed * phi_s * pik;            // lane = k
    a_sr = seed * phi_n * omp;
    a_rr = (1.0f - seed) * phi_n;
    seedRow = (__ballot(seed > 0.f) != 0ull);

    // stage GEMM weights (plain LDS writes)
    wsL[(w << 6) + lane] = fmaf(pik, a_ss, omp * a_sr);
    wrL[(w << 6) + lane] = seedRow ? omp * a_rr : a_rr;

    bowpre = bow[lane * V + v];           // lane = b
    m = __ballot(bowpre > 0.f);

    // ---- phase 1 (lane = b): matvec for s_sum / r_sum ----
    // unroll capped to bound in-flight ds_read temps (spill avoidance)
    float asv = a_ss + a_sr;
    float ss = 0.f, rs = 0.f;
    if (seedRow) {
#pragma unroll 8
      for (int k = 0; k < 64; k++) {
        float th = thetaT_lds[k * 65 + lane];
        ss = fmaf(th, rl(asv, k), ss);
        rs = fmaf(th, rl(a_rr, k), rs);
      }
    } else {
#pragma unroll 8
      for (int k = 0; k < 64; k++) {
        float th = thetaT_lds[k * 65 + lane];
        rs = fmaf(th, rl(a_rr, k), rs);
      }
    }
    ivx = __builtin_amdgcn_rcpf(ss + MINI_C);
    ivy = __builtin_amdgcn_rcpf(rs + MINI_C);
    cisL[(w << 6) + lane] = bowpre * ivx;   // zero for inactive (b,v)
    cirL[(w << 6) + lane] = bowpre * ivy;
  } else {
    wsL[(w << 6) + lane] = 0.f;
    wrL[(w << 6) + lane] = 0.f;
    cisL[(w << 6) + lane] = 0.f;
    cirL[(w << 6) + lane] = 0.f;
  }
  __syncthreads();

  // ---- phase 2 (lane = k): per active b, register-only accumulation ----
  if (active) {
    int rbase = (v << 6) + lane;
    if (seedRow) {
      while (m) {
        int b = __builtin_ctzll(m);
        m &= (m - 1);
        float cb = rl(bowpre, b);
        float is = rl(ivx, b), ir = rl(ivy, b);
        float th = theta_lds[(b << 6) + lane];
        float gss = th * a_ss * is;
        float gsr = th * a_sr * is;
        float grr = th * a_rr * ir;
        float gnr = gsr + grr;
        float gamma = fmaf(pik, gss, omp * gnr);
        acc_n = fmaf(gnr, cb, acc_n);
        acc_s = fmaf(gss, cb, acc_s);
        acc_g += gsr;
        acc_q = fmaf(gamma, __logf(gamma + MINI_C), acc_q);
      }
    } else {
      while (m) {
        int b = __builtin_ctzll(m);
        m &= (m - 1);
        float cb = rl(bowpre, b);
        float ir = rl(ivy, b);
        float th = theta_lds[(b << 6) + lane];
        float grr = th * a_rr * ir;           // gamma == grr
        acc_n = fmaf(grr, cb, acc_n);
        acc_q = fmaf(grr, __logf(grr + MINI_C), acc_q);
      }
    }
    out[4096 + rbase] = acc_n;            // temp_exp_n
    out[4096 + V * 64 + rbase] = acc_s;   // temp_exp_s
  }

  // ---- phase 2b (lane = k): block outer-product partial for temp_exp_m ----
  // P[b,k] = sum_u cis[u][b]*ws[u][k] + cir[u][b]*wr[u][k];  wave w owns b=4w..4w+3
  {
    float acc4x = 0.f, acc4y = 0.f, acc4z = 0.f, acc4w = 0.f;
#pragma unroll 4
    for (int u = 0; u < 16; u++) {
      float wsu = wsL[(u << 6) + lane];
      float wru = wrL[(u << 6) + lane];
      float4 c4 = *(const float4*)&cisL[(u << 6) + (w << 2)];  // broadcast b128
      float4 r4 = *(const float4*)&cirL[(u << 6) + (w << 2)];
      acc4x = fmaf(c4.x, wsu, fmaf(r4.x, wru, acc4x));
      acc4y = fmaf(c4.y, wsu, fmaf(r4.y, wru, acc4y));
      acc4z = fmaf(c4.z, wsu, fmaf(r4.z, wru, acc4z));
      acc4w = fmaf(c4.w, wsu, fmaf(r4.w, wru, acc4w));
    }
    float av[4] = {acc4x, acc4y, acc4z, acc4w};
#pragma unroll
    for (int j = 0; j < 4; j++) {
      int b = (w << 2) + j;
      float val = av[j] * theta_lds[(b << 6) + lane];  // theta multiply (distributive)
      if (useWs) wsm[blockIdx.x * 4096 + (b << 6) + lane] = val;
      else atomicAdd(&out[(b << 6) + lane], val);
    }
  }

  red_gsr[(w << 6) | lane] = acc_g;
  float qz_w = wave_sum(acc_q);
  if (lane == 0) red_qz[w] = qz_w;
  __syncthreads();

  if (w == 0) {
    int gsr_off = 4096 + 2 * V * 64;
    float g = 0.f;
#pragma unroll
    for (int j = 0; j < 16; j++) g += red_gsr[(j << 6) | lane];
    if (useWs) wsg[blockIdx.x * 64 + lane] = g;
    else atomicAdd(&out[gsr_off + lane], g);
    if (t == 0) {
      float q = 0.f;
#pragma unroll
      for (int j = 0; j < 16; j++) q += red_qz[j];
      if (useWs) wsq[blockIdx.x] = q;
      else atomicAdd(&out[gsr_off + 64], q);
    }
  }
}

// ---------- kernel C: parallel reduce of per-block partials ----------
__global__ __launch_bounds__(1024) void reduce_kernel(
    const float* __restrict__ wsm, const float* __restrict__ wsg,
    const float* __restrict__ wsq, float* __restrict__ out,
    int NB, int V) {
  __shared__ float sh[1024];
  int t = threadIdx.x;
  int lane = t & 63, w = t >> 6;
  int bx = blockIdx.x;
  int gsr_off = 4096 + 2 * V * 64;

  if (bx < 64) {
    int e = (bx << 6) + lane;
    float s0 = 0.f, s1 = 0.f, s2 = 0.f, s3 = 0.f;
    int j = w;
    for (; j + 48 < NB; j += 64) {
      s0 += wsm[(size_t)(j)      * 4096 + e];
      s1 += wsm[(size_t)(j + 16) * 4096 + e];
      s2 += wsm[(size_t)(j + 32) * 4096 + e];
      s3 += wsm[(size_t)(j + 48) * 4096 + e];
    }
    for (; j < NB; j += 16) s0 += wsm[(size_t)j * 4096 + e];
    sh[t] = (s0 + s1) + (s2 + s3);
    __syncthreads();
    if (w == 0) {
      float tot = 0.f;
#pragma unroll
      for (int i = 0; i < 16; i++) tot += sh[(i << 6) + lane];
      out[e] = tot;   // out[0..4095] pre-zeroed; single writer per e
    }
  } else if (bx == 64) {
    float s0 = 0.f, s1 = 0.f;
    int j = w;
    for (; j + 16 < NB; j += 32) {
      s0 += wsg[((j) << 6) + lane];
      s1 += wsg[((j + 16) << 6) + lane];
    }
    for (; j < NB; j += 16) s0 += wsg[(j << 6) + lane];
    sh[t] = s0 + s1;
    __syncthreads();
    if (w == 0) {
      float tot = 0.f;
#pragma unroll
      for (int i = 0; i < 16; i++) tot += sh[(i << 6) + lane];
      out[gsr_off + lane] = tot;
    }
  } else {
    float s = 0.f;
    for (int j = t; j < NB; j += 1024) s += wsq[j];
    s = wave_sum(s);
    if (lane == 0) sh[w] = s;
    __syncthreads();
    if (t == 0) {
      float tot = 0.f;
#pragma unroll
      for (int i = 0; i < 16; i++) tot += sh[i];
      out[gsr_off + 64] = tot;
    }
  }
}

extern "C" void kernel_launch(void* const* d_in, const int* in_sizes, int n_in,
                              void* d_out, int out_size, void* d_ws,
                              size_t ws_size, hipStream_t stream) {
  (void)n_in;
  const float* bow   = (const float*)d_in[0];
  const float* seeds = (const float*)d_in[1];
  const float* exp_m = (const float*)d_in[2];
  const float* exp_s = (const float*)d_in[3];
  const float* exp_n = (const float*)d_in[4];
  const float* pi    = (const float*)d_in[5];
  int K = in_sizes[5];          // 64
  int V = in_sizes[1] / K;      // 10000
  float* out = (float*)d_out;
  float* ws = (float*)d_ws;

  int NB = (V + 15) / 16;       // 625 blocks, 16 waves (one v each) per block
  size_t need = (size_t)(256 + (size_t)NB * 4096 + (size_t)NB * 64 + NB) * 4;
  int useWs = (ws_size >= need) ? 1 : 0;

  float* sums = ws;             // 192 floats (+pad)
  float* wsm = ws + 256;        // NB x 4096
  float* wsg = wsm + (size_t)NB * 4096;  // NB x 64
  float* wsq = wsg + (size_t)NB * 64;    // NB

  hipMemsetAsync(d_out, 0, (size_t)out_size * sizeof(float), stream);
  hipMemsetAsync(d_ws, 0, 768, stream);

  int rpb = (V + 255) / 256;
  sums_kernel<<<256, 256, 0, stream>>>(seeds, exp_s, exp_n, sums, V, rpb);
  main_kernel<<<NB, 1024, 0, stream>>>(bow, seeds, exp_m, exp_s, exp_n, pi,
                                       sums, out, wsm, wsg, wsq, V, useWs);
  if (useWs) {
    reduce_kernel<<<66, 1024, 0, stream>>>(wsm, wsg, wsq, out, NB, V);
  }
}